// Round 6
// baseline (270.115 us; speedup 1.0000x reference)
//
#include <hip/hip_runtime.h>

// CovLayer: X [B=64, C=256, T=2048] fp32 -> cov [B, 256, 256] fp32
// Round 10: barrier-free direct-global fragments. r5 counters: 81 µs with
// MfmaUtil 8.8%, VALUBusy 5.3%, HBM 13%, occ 15% -> nothing is busy; the
// 6075 cyc/iter barrier period serializes global->reg->ds_write->barrier->
// ds_read->MFMA latencies (LDS ~1700 + VMEM ~1000 + MFMA ~150 unoverlapped).
// Fix: the 16x16x32 A/B fragment IS 8 contiguous k-floats of a row, and
// lanes {l16,+16,+32,+48} cover one row's 128B contiguously -> load frags
// directly from global (f32x8, perfectly coalesced), cvt to bf16, MFMA.
// No LDS staging, no ds ops, ZERO barriers in the K-loop; 2048 waves
// free-run and overlap latencies. L1/L2 absorb the 2x sibling-wave re-read.
// LDS kept only for the proven epilogue cross-half reduce (2 uniform syncs).
// T5 setprio around the MFMA cluster (free-running waves, attn-like +4-7%).
// Grid: 256 blocks = 64 batches x 4 quadrants (batch->XCD swizzle).

#define NB 64
#define NC 256
#define NT 2048
#define NITER 32        // (NT/2) / 32 per K-half

typedef __bf16 bf16x8 __attribute__((ext_vector_type(8)));
typedef float  f32x8  __attribute__((ext_vector_type(8)));
typedef float  f32x4  __attribute__((ext_vector_type(4)));

__global__ __launch_bounds__(512, 2) void cov_kernel(const float* __restrict__ X,
                                                     float* __restrict__ out) {
    // Epilogue-only LDS: red[4][64*65] + rs[4*64] + cs[4*64] floats = 68.6 KB.
    __shared__ __align__(16) float redF[4 * 64 * 65 + 512];

    const int bid  = blockIdx.x;          // 256 blocks
    const int xcd  = bid & 7;
    const int g    = bid >> 3;            // 0..31
    const int b    = xcd + 8 * (g >> 2);  // batch: 4 quadrants share an XCD
    const int q    = g & 3;               // 128x128 quadrant of 256x256
    const int row0 = (q >> 1) * 128, col0 = (q & 1) * 128;

    const float* __restrict__ Xb = X + (size_t)b * (NC * NT);

    const int t    = threadIdx.x;        // 512 threads = 8 waves
    const int lane = t & 63;
    const int wave = t >> 6;
    const int h    = wave >> 2;          // K-half: [h*1024, h*1024+1024)
    const int wq   = wave & 3;
    const int wm   = wq >> 1, wn = wq & 1;   // 2x2 waves, 64x64 each
    const int quad = lane >> 4;
    const int l16  = lane & 15;

    // Per-thread fragment base pointers. A-frag for (mt): row = row0+wm*64+
    // mt*16+l16, k = h*1024 + k*32 + quad*8. Lanes {l16,l16+16,l16+32,l16+48}
    // jointly read one row's 32 floats (128B contiguous) -> coalesced.
    const float* aP[4];
    const float* bP[4];
#pragma unroll
    for (int mt = 0; mt < 4; ++mt)
        aP[mt] = Xb + (size_t)(row0 + wm * 64 + mt * 16 + l16) * NT + h * (NT / 2) + quad * 8;
#pragma unroll
    for (int nt = 0; nt < 4; ++nt)
        bP[nt] = Xb + (size_t)(col0 + wn * 64 + nt * 16 + l16) * NT + h * (NT / 2) + quad * 8;

    f32x4 acc[4][4], accRS[4], accCS[4];
#pragma unroll
    for (int i = 0; i < 4; ++i) {
        accRS[i] = (f32x4){0.f, 0.f, 0.f, 0.f};
        accCS[i] = (f32x4){0.f, 0.f, 0.f, 0.f};
#pragma unroll
        for (int j = 0; j < 4; ++j) acc[i][j] = (f32x4){0.f, 0.f, 0.f, 0.f};
    }
    const bf16x8 ones = {(__bf16)1.0f, (__bf16)1.0f, (__bf16)1.0f, (__bf16)1.0f,
                         (__bf16)1.0f, (__bf16)1.0f, (__bf16)1.0f, (__bf16)1.0f};

    // Barrier-free K-loop: loads of iter k+1 are independent of iter k's
    // MFMAs; unroll 2 lets the scheduler software-pipeline them freely.
#pragma unroll 2
    for (int k = 0; k < NITER; ++k) {
        f32x8 a32[4], b32[4];
#pragma unroll
        for (int mt = 0; mt < 4; ++mt) a32[mt] = *(const f32x8*)(aP[mt] + k * 32);
#pragma unroll
        for (int nt = 0; nt < 4; ++nt) b32[nt] = *(const f32x8*)(bP[nt] + k * 32);

        bf16x8 aF[4], bF[4];
#pragma unroll
        for (int mt = 0; mt < 4; ++mt) aF[mt] = __builtin_convertvector(a32[mt], bf16x8);
#pragma unroll
        for (int nt = 0; nt < 4; ++nt) bF[nt] = __builtin_convertvector(b32[nt], bf16x8);

        __builtin_amdgcn_s_setprio(1);
#pragma unroll
        for (int mt = 0; mt < 4; ++mt) {
            accRS[mt] = __builtin_amdgcn_mfma_f32_16x16x32_bf16(aF[mt], ones, accRS[mt], 0, 0, 0);
#pragma unroll
            for (int nt = 0; nt < 4; ++nt)
                acc[mt][nt] = __builtin_amdgcn_mfma_f32_16x16x32_bf16(aF[mt], bF[nt], acc[mt][nt], 0, 0, 0);
        }
#pragma unroll
        for (int nt = 0; nt < 4; ++nt)
            accCS[nt] = __builtin_amdgcn_mfma_f32_16x16x32_bf16(ones, bF[nt], accCS[nt], 0, 0, 0);
        __builtin_amdgcn_s_setprio(0);
    }

    // Epilogue: combine the two K-halves. h=1 dumps to LDS; h=0 reduces+stores.
    float* red = redF + wq * (64 * 65);
    float* rs  = redF + 4 * (64 * 65);       // [4][64]
    float* cs  = rs + 256;                   // [4][64]

    if (h == 1) {
#pragma unroll
        for (int mt = 0; mt < 4; ++mt)
#pragma unroll
            for (int nt = 0; nt < 4; ++nt)
#pragma unroll
                for (int r = 0; r < 4; ++r)
                    red[(mt * 16 + quad * 4 + r) * 65 + nt * 16 + l16] = acc[mt][nt][r];
        if (l16 == 0) {
#pragma unroll
            for (int mt = 0; mt < 4; ++mt)
#pragma unroll
                for (int r = 0; r < 4; ++r)
                    rs[wq * 64 + mt * 16 + quad * 4 + r] = accRS[mt][r];
        }
        if (quad == 0) {
#pragma unroll
            for (int nt = 0; nt < 4; ++nt)
                cs[wq * 64 + nt * 16 + l16] = accCS[nt][0];
        }
    }
    __syncthreads();

    if (h == 0) {
        const float invT = 1.0f / NT;
        float* __restrict__ outB = out + (size_t)b * (NC * NC);
#pragma unroll
        for (int mt = 0; mt < 4; ++mt) {
#pragma unroll
            for (int nt = 0; nt < 4; ++nt) {
#pragma unroll
                for (int r = 0; r < 4; ++r) {
                    const int R = mt * 16 + quad * 4 + r;
                    const int C = nt * 16 + l16;
                    const float tot = red[R * 65 + C] + acc[mt][nt][r];
                    const float Sx  = rs[wq * 64 + R] + accRS[mt][r];
                    const float Sy  = cs[wq * 64 + C] + accCS[nt][0];
                    outB[(size_t)(row0 + wm * 64 + R) * NC + (col0 + wn * 64 + C)] =
                        (tot - Sx * Sy * invT) * invT;
                }
            }
        }
    }
}

extern "C" void kernel_launch(void* const* d_in, const int* in_sizes, int n_in,
                              void* d_out, int out_size, void* d_ws, size_t ws_size,
                              hipStream_t stream) {
    const float* X = (const float*)d_in[0];
    float* out = (float*)d_out;
    (void)in_sizes; (void)n_in; (void)out_size; (void)d_ws; (void)ws_size;
    cov_kernel<<<256, 512, 0, stream>>>(X, out);
}

// Round 7
// 219.273 us; speedup vs baseline: 1.2319x; 1.2319x over previous
//
#include <hip/hip_runtime.h>

// CovLayer: X [B=64, C=256, T=2048] fp32 -> cov [B, 256, 256] fp32
// Round 11: r0 structure (LDS staging + plain __syncthreads, 4-quadrant,
// 8 waves = 2x2 spatial x split-K 2, dbuf, prefetch depth 2) with BK 32->64:
// 16 barrier periods instead of 32. Evidence: r0/r2 both 43.5 µs at 537/268 MB
// traffic (barrier-period-bound, not BW); r5's pinned barriers 81 µs (hands
// off the scheduler); r6 free-run 7.3 TB/s but 4x traffic (137 µs).
// BK=64 -> 128-B LDS rows = 16-way ds_read_b128 conflict, so T2 XOR-swizzle
// byte ^= ((row&7)<<4) on BOTH staging writes and fragment reads (involution;
// reg-staged path so no global_load_lds constraint). ksub composed by XOR
// (^(ksub<<6)), mt by +mt*2048: neither carries into the swizzle bits.

#define NB 64
#define NC 256
#define NT 2048
#define BK 64
#define NITER 16        // (NT/2) / BK per K-half

typedef __bf16 bf16x8 __attribute__((ext_vector_type(8)));
typedef float  f32x8  __attribute__((ext_vector_type(8)));
typedef float  f32x4  __attribute__((ext_vector_type(4)));

__global__ __launch_bounds__(512, 2) void cov_kernel(const float* __restrict__ X,
                                                     float* __restrict__ out) {
    // Staging: A [2 buf][2 half][128x64] bf16 = 64 KB, B same at +64 KB = 128 KB.
    // Epilogue overlay: red[4][64*65] + rs[256] + cs[256] = 68.6 KB (reused).
    __shared__ __align__(16) unsigned char smem[131072];
    char*  sbase = (char*)smem;
    float* redF  = (float*)smem;

    const int bid  = blockIdx.x;          // 256 blocks
    const int xcd  = bid & 7;
    const int g    = bid >> 3;            // 0..31
    const int b    = xcd + 8 * (g >> 2);  // batch: 4 quadrants share an XCD
    const int q    = g & 3;               // 128x128 quadrant of 256x256
    const int row0 = (q >> 1) * 128, col0 = (q & 1) * 128;

    const float* __restrict__ Xb = X + (size_t)b * (NC * NT);

    const int t    = threadIdx.x;        // 512 threads = 8 waves
    const int lane = t & 63;
    const int wave = t >> 6;
    const int h    = wave >> 2;          // K-half: [h*1024, h*1024+1024)
    const int wq   = wave & 3;
    const int wm   = wq >> 1, wn = wq & 1;   // 2x2 waves, 64x64 each
    const int quad = lane >> 4;
    const int l16  = lane & 15;

    // Staging: 256 threads per half; thread u covers row sr, float cols
    // [scf, scf+32) of the 64-float k-window, as 4 f32x8 loads.
    const int u   = t & 255;
    const int sr  = u >> 1;              // 0..127
    const int scf = (u & 1) * 32;        // 0 or 32
    const float* gA = Xb + (size_t)(row0 + sr) * NT + h * (NT / 2) + scf;
    const float* gB = Xb + (size_t)(col0 + sr) * NT + h * (NT / 2) + scf;

    // Panel byte-bases: A(h,buf) and B(h,buf), 16 KB per panel.
    char* pa[2] = { sbase +         (0 * 2 + h) * 16384,
                    sbase +         (1 * 2 + h) * 16384 };
    char* pb[2] = { sbase + 65536 + (0 * 2 + h) * 16384,
                    sbase + 65536 + (1 * 2 + h) * 16384 };

    // Swizzled write offsets (involution ^((row&7)<<4), within-row bits only).
    int wOff[4];
#pragma unroll
    for (int j = 0; j < 4; ++j)
        wOff[j] = (sr * 128 + scf * 2 + j * 16) ^ ((sr & 7) << 4);

    // Swizzled read bases: row*128 + quad*16, same involution (row&7 == l16&7).
    const int aB0 = ((wm * 64 + l16) * 128 + quad * 16) ^ ((l16 & 7) << 4);
    const int bB0 = ((wn * 64 + l16) * 128 + quad * 16) ^ ((l16 & 7) << 4);

    f32x4 acc[4][4], accRS[4], accCS[4];
#pragma unroll
    for (int i = 0; i < 4; ++i) {
        accRS[i] = (f32x4){0.f, 0.f, 0.f, 0.f};
        accCS[i] = (f32x4){0.f, 0.f, 0.f, 0.f};
#pragma unroll
        for (int j = 0; j < 4; ++j) acc[i][j] = (f32x4){0.f, 0.f, 0.f, 0.f};
    }
    const bf16x8 ones = {(__bf16)1.0f, (__bf16)1.0f, (__bf16)1.0f, (__bf16)1.0f,
                         (__bf16)1.0f, (__bf16)1.0f, (__bf16)1.0f, (__bf16)1.0f};

    // Prologue: load+stage iter 0 into buf0, prefetch iter 1 into p.
    f32x8 pA[4], pB[4];
#pragma unroll
    for (int j = 0; j < 4; ++j) {
        pA[j] = *(const f32x8*)(gA + j * 8);
        pB[j] = *(const f32x8*)(gB + j * 8);
    }
#pragma unroll
    for (int j = 0; j < 4; ++j) {
        *(bf16x8*)(pa[0] + wOff[j]) = __builtin_convertvector(pA[j], bf16x8);
        *(bf16x8*)(pb[0] + wOff[j]) = __builtin_convertvector(pB[j], bf16x8);
    }
#pragma unroll
    for (int j = 0; j < 4; ++j) {
        pA[j] = *(const f32x8*)(gA + BK + j * 8);
        pB[j] = *(const f32x8*)(gB + BK + j * 8);
    }
    __syncthreads();

#pragma unroll 2
    for (int k = 0; k < NITER; ++k) {
        const int cur = k & 1, nxt = cur ^ 1;

        // Stage iter k+1 (in regs, issued one full iteration ago).
        if (k + 1 < NITER) {
#pragma unroll
            for (int j = 0; j < 4; ++j) {
                *(bf16x8*)(pa[nxt] + wOff[j]) = __builtin_convertvector(pA[j], bf16x8);
                *(bf16x8*)(pb[nxt] + wOff[j]) = __builtin_convertvector(pB[j], bf16x8);
            }
        }
        // Prefetch iter k+2 (drained at this iter's trailing barrier, ~450+
        // cycles after issue: mostly hidden under ds_read + MFMA phase).
        if (k + 2 < NITER) {
#pragma unroll
            for (int j = 0; j < 4; ++j) {
                pA[j] = *(const f32x8*)(gA + (k + 2) * BK + j * 8);
                pB[j] = *(const f32x8*)(gB + (k + 2) * BK + j * 8);
            }
        }

        // Two 32-k MFMA steps per staged 64-k tile.
#pragma unroll
        for (int ksub = 0; ksub < 2; ++ksub) {
            bf16x8 aF[4], bF[4];
#pragma unroll
            for (int mt = 0; mt < 4; ++mt)
                aF[mt] = *(const bf16x8*)(pa[cur] + ((aB0 + mt * 2048) ^ (ksub << 6)));
#pragma unroll
            for (int nt = 0; nt < 4; ++nt)
                bF[nt] = *(const bf16x8*)(pb[cur] + ((bB0 + nt * 2048) ^ (ksub << 6)));

#pragma unroll
            for (int mt = 0; mt < 4; ++mt) {
                accRS[mt] = __builtin_amdgcn_mfma_f32_16x16x32_bf16(aF[mt], ones, accRS[mt], 0, 0, 0);
#pragma unroll
                for (int nt = 0; nt < 4; ++nt)
                    acc[mt][nt] = __builtin_amdgcn_mfma_f32_16x16x32_bf16(aF[mt], bF[nt], acc[mt][nt], 0, 0, 0);
            }
#pragma unroll
            for (int nt = 0; nt < 4; ++nt)
                accCS[nt] = __builtin_amdgcn_mfma_f32_16x16x32_bf16(ones, bF[nt], accCS[nt], 0, 0, 0);
        }

        __syncthreads();   // one barrier per 64-k period (16 total)
    }

    // Epilogue: combine the two K-halves. h=1 dumps to LDS; h=0 reduces+stores.
    float* red = redF + wq * (64 * 65);
    float* rs  = redF + 4 * (64 * 65);       // [4][64]
    float* cs  = rs + 256;                   // [4][64]

    if (h == 1) {
#pragma unroll
        for (int mt = 0; mt < 4; ++mt)
#pragma unroll
            for (int nt = 0; nt < 4; ++nt)
#pragma unroll
                for (int r = 0; r < 4; ++r)
                    red[(mt * 16 + quad * 4 + r) * 65 + nt * 16 + l16] = acc[mt][nt][r];
        if (l16 == 0) {
#pragma unroll
            for (int mt = 0; mt < 4; ++mt)
#pragma unroll
                for (int r = 0; r < 4; ++r)
                    rs[wq * 64 + mt * 16 + quad * 4 + r] = accRS[mt][r];
        }
        if (quad == 0) {
#pragma unroll
            for (int nt = 0; nt < 4; ++nt)
                cs[wq * 64 + nt * 16 + l16] = accCS[nt][0];
        }
    }
    __syncthreads();

    if (h == 0) {
        const float invT = 1.0f / NT;
        float* __restrict__ outB = out + (size_t)b * (NC * NC);
#pragma unroll
        for (int mt = 0; mt < 4; ++mt) {
#pragma unroll
            for (int nt = 0; nt < 4; ++nt) {
#pragma unroll
                for (int r = 0; r < 4; ++r) {
                    const int R = mt * 16 + quad * 4 + r;
                    const int C = nt * 16 + l16;
                    const float tot = red[R * 65 + C] + acc[mt][nt][r];
                    const float Sx  = rs[wq * 64 + R] + accRS[mt][r];
                    const float Sy  = cs[wq * 64 + C] + accCS[nt][0];
                    outB[(size_t)(row0 + wm * 64 + R) * NC + (col0 + wn * 64 + C)] =
                        (tot - Sx * Sy * invT) * invT;
                }
            }
        }
    }
}

extern "C" void kernel_launch(void* const* d_in, const int* in_sizes, int n_in,
                              void* d_out, int out_size, void* d_ws, size_t ws_size,
                              hipStream_t stream) {
    const float* X = (const float*)d_in[0];
    float* out = (float*)d_out;
    (void)in_sizes; (void)n_in; (void)out_size; (void)d_ws; (void)ws_size;
    cov_kernel<<<256, 512, 0, stream>>>(X, out);
}

// Round 8
// 211.054 us; speedup vs baseline: 1.2798x; 1.0389x over previous
//
#include <hip/hip_runtime.h>

// CovLayer: X [B=64, C=256, T=2048] fp32 -> cov [B, 256, 256] fp32
// Round 12: traffic reduction at the measured fabric roofline.
// Evidence: staged kernels stream at 10.4 B/cyc/CU (r5: 6075cyc/period @64KB;
// r7: 12600 @128KB) = 6.4 TB/s aggregate = m13 ceiling, even L3-resident.
// Barrier count / type / MFMA all secondary. So: cut traffic 537->192 MB.
// Per batch 4 blocks: diag0/diag1 (A==B panel, full K, 524 KB reads each,
// write corrected quadrant directly) + off-diag split by K into 2 blocks
// (1 MB reads each, write 64KB f32 partial Gram + row/col sums to ws).
// cov_fix (256 blocks) reduces partials, applies mean correction, writes
// (0,1) and mirrored (1,0) via LDS transpose (~17 MB total).
// Microstructure = r7 verbatim: BK=64, T2 XOR-swizzle both sides, dbuf,
// reg prefetch depth 2, plain __syncthreads per period.

#define NB 64
#define NC 256
#define NT 2048
#define BK 64
#define WSB 33280   // floats per batch in ws: 2*16384 P + 4*128 sums

typedef __bf16 bf16x8 __attribute__((ext_vector_type(8)));
typedef float  f32x8  __attribute__((ext_vector_type(8)));
typedef float  f32x4  __attribute__((ext_vector_type(4)));

__global__ __launch_bounds__(512, 2) void cov_gram(const float* __restrict__ X,
                                                   float* __restrict__ out,
                                                   float* __restrict__ ws) {
    // Staging: A [2 buf][2 half][128x64] bf16 = 64 KB (+B at +64 KB for off).
    // Epilogue overlay: red[4][64*65] + rs[256] + cs[256] = 68.6 KB (reused).
    __shared__ __align__(16) unsigned char smem[131072];
    char*  sbase = (char*)smem;
    float* redF  = (float*)smem;

    const int bid  = blockIdx.x;          // 256 blocks
    const int xcd  = bid & 7;
    const int g    = bid >> 3;            // 0..31
    const int b    = xcd + 8 * (g >> 2);  // batch: its 4 blocks share an XCD
    const int role = g & 3;               // 0,1: diag quadrant; 2,3: off K-half
    const bool diag = (role < 2);

    const float* __restrict__ Xb = X + (size_t)b * (NC * NT);

    const int t    = threadIdx.x;        // 512 threads = 8 waves
    const int lane = t & 63;
    const int wave = t >> 6;
    const int h    = wave >> 2;          // in-block split-K half
    const int wq   = wave & 3;
    const int wm   = wq >> 1, wn = wq & 1;   // 2x2 waves, 64x64 each
    const int quad = lane >> 4;
    const int l16  = lane & 15;

    // Per-role geometry: diag reads 128 rows x full K (A==B, 524 KB);
    // off reads 256 rows x K=1024 (1 MB), window chosen by role&1.
    const int niter = diag ? 16 : 8;
    const int kb    = diag ? h * 1024 : (role & 1) * 1024 + h * 512;
    const int ar0   = diag ? role * 128 : 0;

    // Staging: 256 threads/half; thread u: row sr, float cols [scf,scf+32).
    const int u   = t & 255;
    const int sr  = u >> 1;              // 0..127
    const int scf = (u & 1) * 32;
    const float* gA = Xb + (size_t)(ar0 + sr) * NT + kb + scf;
    const float* gB = Xb + (size_t)(128 + sr) * NT + kb + scf;  // off only

    char* pa[2] = { sbase + (0 * 2 + h) * 16384, sbase + (1 * 2 + h) * 16384 };
    char* pb[2];
    if (diag) { pb[0] = pa[0]; pb[1] = pa[1]; }     // B-panel == A-panel
    else {
        pb[0] = sbase + 65536 + (0 * 2 + h) * 16384;
        pb[1] = sbase + 65536 + (1 * 2 + h) * 16384;
    }

    // T2 swizzle (involution ^((row&7)<<4)); proven conflict-free in r7.
    int wOff[4];
#pragma unroll
    for (int j = 0; j < 4; ++j)
        wOff[j] = (sr * 128 + scf * 2 + j * 16) ^ ((sr & 7) << 4);
    const int aB0 = ((wm * 64 + l16) * 128 + quad * 16) ^ ((l16 & 7) << 4);
    const int bB0 = ((wn * 64 + l16) * 128 + quad * 16) ^ ((l16 & 7) << 4);

    f32x4 acc[4][4], accRS[4], accCS[4];
#pragma unroll
    for (int i = 0; i < 4; ++i) {
        accRS[i] = (f32x4){0.f, 0.f, 0.f, 0.f};
        accCS[i] = (f32x4){0.f, 0.f, 0.f, 0.f};
#pragma unroll
        for (int j = 0; j < 4; ++j) acc[i][j] = (f32x4){0.f, 0.f, 0.f, 0.f};
    }
    const bf16x8 ones = {(__bf16)1.0f, (__bf16)1.0f, (__bf16)1.0f, (__bf16)1.0f,
                         (__bf16)1.0f, (__bf16)1.0f, (__bf16)1.0f, (__bf16)1.0f};

    // Prologue: load+stage iter 0 into buf0, prefetch iter 1 into regs.
    f32x8 pA[4], pB[4];
#pragma unroll
    for (int j = 0; j < 4; ++j) pA[j] = *(const f32x8*)(gA + j * 8);
    if (!diag) {
#pragma unroll
        for (int j = 0; j < 4; ++j) pB[j] = *(const f32x8*)(gB + j * 8);
    }
#pragma unroll
    for (int j = 0; j < 4; ++j)
        *(bf16x8*)(pa[0] + wOff[j]) = __builtin_convertvector(pA[j], bf16x8);
    if (!diag) {
#pragma unroll
        for (int j = 0; j < 4; ++j)
            *(bf16x8*)(pb[0] + wOff[j]) = __builtin_convertvector(pB[j], bf16x8);
    }
#pragma unroll
    for (int j = 0; j < 4; ++j) pA[j] = *(const f32x8*)(gA + BK + j * 8);
    if (!diag) {
#pragma unroll
        for (int j = 0; j < 4; ++j) pB[j] = *(const f32x8*)(gB + BK + j * 8);
    }
    __syncthreads();

#pragma unroll 2
    for (int k = 0; k < niter; ++k) {
        const int cur = k & 1, nxt = cur ^ 1;

        if (k + 1 < niter) {
#pragma unroll
            for (int j = 0; j < 4; ++j)
                *(bf16x8*)(pa[nxt] + wOff[j]) = __builtin_convertvector(pA[j], bf16x8);
            if (!diag) {
#pragma unroll
                for (int j = 0; j < 4; ++j)
                    *(bf16x8*)(pb[nxt] + wOff[j]) = __builtin_convertvector(pB[j], bf16x8);
            }
        }
        if (k + 2 < niter) {
#pragma unroll
            for (int j = 0; j < 4; ++j)
                pA[j] = *(const f32x8*)(gA + (k + 2) * BK + j * 8);
            if (!diag) {
#pragma unroll
                for (int j = 0; j < 4; ++j)
                    pB[j] = *(const f32x8*)(gB + (k + 2) * BK + j * 8);
            }
        }

#pragma unroll
        for (int ksub = 0; ksub < 2; ++ksub) {
            bf16x8 aF[4], bF[4];
#pragma unroll
            for (int mt = 0; mt < 4; ++mt)
                aF[mt] = *(const bf16x8*)(pa[cur] + ((aB0 + mt * 2048) ^ (ksub << 6)));
#pragma unroll
            for (int nt = 0; nt < 4; ++nt)
                bF[nt] = *(const bf16x8*)(pb[cur] + ((bB0 + nt * 2048) ^ (ksub << 6)));

#pragma unroll
            for (int mt = 0; mt < 4; ++mt) {
                accRS[mt] = __builtin_amdgcn_mfma_f32_16x16x32_bf16(aF[mt], ones, accRS[mt], 0, 0, 0);
#pragma unroll
                for (int nt = 0; nt < 4; ++nt)
                    acc[mt][nt] = __builtin_amdgcn_mfma_f32_16x16x32_bf16(aF[mt], bF[nt], acc[mt][nt], 0, 0, 0);
            }
#pragma unroll
            for (int nt = 0; nt < 4; ++nt)
                accCS[nt] = __builtin_amdgcn_mfma_f32_16x16x32_bf16(ones, bF[nt], accCS[nt], 0, 0, 0);
        }

        __syncthreads();
    }

    // Cross-half combine: h=1 dumps to LDS; h=0 reduces and emits.
    float* red = redF + wq * (64 * 65);
    float* rs  = redF + 4 * (64 * 65);       // [4][64]
    float* cs  = rs + 256;                   // [4][64]

    if (h == 1) {
#pragma unroll
        for (int mt = 0; mt < 4; ++mt)
#pragma unroll
            for (int nt = 0; nt < 4; ++nt)
#pragma unroll
                for (int r = 0; r < 4; ++r)
                    red[(mt * 16 + quad * 4 + r) * 65 + nt * 16 + l16] = acc[mt][nt][r];
        if (l16 == 0) {
#pragma unroll
            for (int mt = 0; mt < 4; ++mt)
#pragma unroll
                for (int r = 0; r < 4; ++r)
                    rs[wq * 64 + mt * 16 + quad * 4 + r] = accRS[mt][r];
        }
        if (quad == 0) {
#pragma unroll
            for (int nt = 0; nt < 4; ++nt)
                cs[wq * 64 + nt * 16 + l16] = accCS[nt][0];
        }
    }
    __syncthreads();

    if (h == 0) {
        if (diag) {
            // Full K in-block: correct and write the diag quadrant directly.
            const float invT = 1.0f / NT;
            const int row0 = role * 128, col0 = role * 128;
            float* __restrict__ outB = out + (size_t)b * (NC * NC);
#pragma unroll
            for (int mt = 0; mt < 4; ++mt) {
#pragma unroll
                for (int nt = 0; nt < 4; ++nt) {
#pragma unroll
                    for (int r = 0; r < 4; ++r) {
                        const int R = mt * 16 + quad * 4 + r;
                        const int C = nt * 16 + l16;
                        const float tot = red[R * 65 + C] + acc[mt][nt][r];
                        const float Sx  = rs[wq * 64 + R] + accRS[mt][r];
                        const float Sy  = cs[wq * 64 + C] + accCS[nt][0];
                        outB[(size_t)(row0 + wm * 64 + R) * NC + (col0 + wn * 64 + C)] =
                            (tot - Sx * Sy * invT) * invT;
                    }
                }
            }
        } else {
            // K-half partial: raw Gram + this window's row/col sums to ws.
            const int half = role & 1;
            float* __restrict__ wsP = ws + (size_t)b * WSB + (size_t)half * 16384;
            float* __restrict__ sxW = ws + (size_t)b * WSB + 32768 + half * 128;
            float* __restrict__ syW = ws + (size_t)b * WSB + 33024 + half * 128;
#pragma unroll
            for (int mt = 0; mt < 4; ++mt) {
#pragma unroll
                for (int nt = 0; nt < 4; ++nt) {
#pragma unroll
                    for (int r = 0; r < 4; ++r) {
                        const int R = mt * 16 + quad * 4 + r;
                        const int C = nt * 16 + l16;
                        wsP[(size_t)(wm * 64 + R) * 128 + wn * 64 + C] =
                            red[R * 65 + C] + acc[mt][nt][r];
                    }
                }
            }
            if (l16 == 0 && wn == 0) {
#pragma unroll
                for (int mt = 0; mt < 4; ++mt)
#pragma unroll
                    for (int r = 0; r < 4; ++r) {
                        const int R = mt * 16 + quad * 4 + r;
                        sxW[wm * 64 + R] = rs[wq * 64 + R] + accRS[mt][r];
                    }
            }
            if (quad == 0 && wm == 0) {
#pragma unroll
                for (int nt = 0; nt < 4; ++nt) {
                    const int C = nt * 16 + l16;
                    syW[wn * 64 + C] = cs[wq * 64 + C] + accCS[nt][0];
                }
            }
        }
    }
}

__global__ __launch_bounds__(256) void cov_fix(const float* __restrict__ ws,
                                               float* __restrict__ out) {
    // Reduce the two off-diag K-half partials, apply mean correction, write
    // quadrant (0,1) and its transpose (1,0). 4 blocks/batch, 32 rows each.
    __shared__ float tile[32][133];
    const int bid = blockIdx.x;          // 256 blocks
    const int b   = bid >> 2;
    const int c0  = (bid & 3) * 32;      // row chunk within the quadrant
    const float* __restrict__ wsB = ws + (size_t)b * WSB;
    const float* __restrict__ P0  = wsB;
    const float* __restrict__ P1  = wsB + 16384;
    const float* sx0 = wsB + 32768; const float* sx1 = sx0 + 128;
    const float* sy0 = wsB + 33024; const float* sy1 = sy0 + 128;
    float* __restrict__ outB = out + (size_t)b * (NC * NC);
    const float invT = 1.0f / NT;
    const int tid = threadIdx.x;

#pragma unroll
    for (int j = 0; j < 4; ++j) {
        const int idx = tid + j * 256;   // 0..1023
        const int ri  = idx >> 5;        // 0..31
        const int c4  = (idx & 31) * 4;  // 0..124
        const int R   = c0 + ri;
        f32x4 s = *(const f32x4*)&P0[(size_t)R * 128 + c4];
        s += *(const f32x4*)&P1[(size_t)R * 128 + c4];
        const float Sx = sx0[R] + sx1[R];
        f32x4 Sy = *(const f32x4*)&sy0[c4];
        Sy += *(const f32x4*)&sy1[c4];
        const f32x4 v = (s - Sy * (Sx * invT)) * invT;
        *(f32x4*)&outB[(size_t)R * NC + 128 + c4] = v;
        tile[ri][c4 + 0] = v[0]; tile[ri][c4 + 1] = v[1];
        tile[ri][c4 + 2] = v[2]; tile[ri][c4 + 3] = v[3];
    }
    __syncthreads();
#pragma unroll
    for (int j = 0; j < 4; ++j) {
        const int idx = tid + j * 256;
        const int mr  = idx >> 3;        // 0..127 (quadrant col -> out row 128+mr)
        const int mc  = (idx & 7) * 4;   // 0..28  (row offset within chunk)
        const f32x4 v = { tile[mc + 0][mr], tile[mc + 1][mr],
                          tile[mc + 2][mr], tile[mc + 3][mr] };
        *(f32x4*)&outB[(size_t)(128 + mr) * NC + c0 + mc] = v;
    }
}

extern "C" void kernel_launch(void* const* d_in, const int* in_sizes, int n_in,
                              void* d_out, int out_size, void* d_ws, size_t ws_size,
                              hipStream_t stream) {
    const float* X = (const float*)d_in[0];
    float* out = (float*)d_out;
    float* ws = (float*)d_ws;
    (void)in_sizes; (void)n_in; (void)out_size; (void)ws_size;
    cov_gram<<<256, 512, 0, stream>>>(X, out, ws);
    cov_fix<<<256, 256, 0, stream>>>(ws, out);
}